// Round 6
// baseline (82.170 us; speedup 1.0000x reference)
//
#include <hip/hip_runtime.h>
#include <stdint.h>
#include <stddef.h>

#define BATCH 256
#define IN_F  4096
#define OUT_F 4096
#define KSPLIT 4

typedef __attribute__((ext_vector_type(8))) short    bf16x8;
typedef __attribute__((ext_vector_type(4))) float    f32x4;
typedef __attribute__((ext_vector_type(2))) uint32_t u32x2;
typedef __attribute__((ext_vector_type(4))) uint32_t u32x4;

#define MFMA(a,b,c) __builtin_amdgcn_mfma_f32_16x16x32_bf16((a),(b),(c),0,0,0)
#define HALF_LOG2E 0.7213475204444817f   // exp(0.5*x) == exp2(x*HALF_LOG2E)

__device__ __forceinline__ uint32_t pack2bf(float a, float b) {
  uint32_t ua = __builtin_bit_cast(uint32_t, a);
  uint32_t ub = __builtin_bit_cast(uint32_t, b);
  ua += 0x7FFFu + ((ua >> 16) & 1u);
  ub += 0x7FFFu + ((ub >> 16) & 1u);
  return (ua >> 16) | (ub & 0xFFFF0000u);
}

__device__ __forceinline__ bf16x8 cvt8(const float* p) {
  f32x4 v0 = *(const f32x4*)p;
  f32x4 v1 = *(const f32x4*)(p + 4);
  union { u32x4 u; bf16x8 h; } r;
  r.u[0] = pack2bf(v0[0], v0[1]); r.u[1] = pack2bf(v0[2], v0[3]);
  r.u[2] = pack2bf(v1[0], v1[1]); r.u[3] = pack2bf(v1[2], v1[3]);
  return r.h;
}

__device__ __forceinline__ void gload_lds16(const void* g, void* l) {
  __builtin_amdgcn_global_load_lds(
      (const __attribute__((address_space(1))) uint32_t*)g,
      (__attribute__((address_space(3))) uint32_t*)l, 16, 0, 0);
}

// ---------------------------------------------------------------------------
// Persistent streaming pass: W = mu + eps*exp(.5*lv) -> bf16 tile images
// (layout identical to R4/R5 validated); x -> bf16; bias.
// Duty-cycle fix: 1024 persistent W-blocks, 8 units each, software-pipelined
// (issue unit t+1's 6 loads BEFORE converting/storing unit t) -> reads
// outstanding ~continuously; no barriers, no mid-kernel drains.
// Unit = half W row = 2048 floats/array. Thread owns 8 consecutive floats
// -> one full 16B output granule (single dwordx4 store, swizzle baked in).
// ---------------------------------------------------------------------------
#define WBLKP 1024   // persistent W blocks
#define UPB   8      // units per block (8192 units total)
#define XBLK  512    // x blocks: 512 x 2048 floats
#define HLG HALF_LOG2E

__global__ __launch_bounds__(256) void wcvt_persist(
    const float* __restrict__ wmu,
    const float* __restrict__ wlv,
    const float* __restrict__ weps,
    const float* __restrict__ x,
    const float* __restrict__ bmu,
    const float* __restrict__ blv,
    const float* __restrict__ beps,
    uint8_t*  __restrict__ wimg,
    uint8_t*  __restrict__ xs,
    float*    __restrict__ bias)
{
  const uint32_t b = blockIdx.x;
  const int      t = threadIdx.x;

  if (b < WBLKP) {
    // ---- persistent, pipelined W stream ----
    f32x4 am0, am1, av0, av1, ae0, ae1;    // set A
    f32x4 bm0, bm1, bv0, bv1, be0, be1;    // set B

#define GOFS(u) ((size_t)((u) >> 1) * 4096u + (size_t)((u) & 1) * 2048u + 8u * (uint32_t)t)
#define LOADS(M0,M1,V0,V1,E0,E1,u) do {                    \
    const size_t _o = GOFS(u);                             \
    M0 = *(const f32x4*)(wmu  + _o); M1 = *(const f32x4*)(wmu  + _o + 4); \
    V0 = *(const f32x4*)(wlv  + _o); V1 = *(const f32x4*)(wlv  + _o + 4); \
    E0 = *(const f32x4*)(weps + _o); E1 = *(const f32x4*)(weps + _o + 4); \
  } while (0)
#define CONVST(M0,M1,V0,V1,E0,E1,u) do {                                   \
    u32x4 _o4;                                                             \
    _o4[0] = pack2bf(fmaf(E0[0], exp2f(V0[0]*HLG), M0[0]),                 \
                     fmaf(E0[1], exp2f(V0[1]*HLG), M0[1]));                \
    _o4[1] = pack2bf(fmaf(E0[2], exp2f(V0[2]*HLG), M0[2]),                 \
                     fmaf(E0[3], exp2f(V0[3]*HLG), M0[3]));                \
    _o4[2] = pack2bf(fmaf(E1[0], exp2f(V1[0]*HLG), M1[0]),                 \
                     fmaf(E1[1], exp2f(V1[1]*HLG), M1[1]));                \
    _o4[3] = pack2bf(fmaf(E1[2], exp2f(V1[2]*HLG), M1[2]),                 \
                     fmaf(E1[3], exp2f(V1[3]*HLG), M1[3]));                \
    const uint32_t _n  = (u) >> 1,  _h = (u) & 1;                          \
    const uint32_t _r  = _n & 15u,  _nt = _n >> 4;                         \
    const uint32_t _kt = _h * 16u + ((uint32_t)t >> 4);                    \
    const uint32_t _g  = (uint32_t)t & 15u;                                \
    *(u32x4*)(wimg + (((size_t)(_nt * 32u + _kt)) << 12)                   \
                   + (_r << 8) + (((_g ^ _r) & 15u) << 4)) = _o4;          \
  } while (0)

    LOADS(am0, am1, av0, av1, ae0, ae1, b);        // prologue: unit 0 -> A
#pragma unroll
    for (int i = 0; i < UPB; ++i) {
      const uint32_t u  = b + (uint32_t)i * WBLKP;
      const uint32_t un = u + WBLKP;
      if ((i & 1) == 0) {
        if (i + 1 < UPB) LOADS(bm0, bm1, bv0, bv1, be0, be1, un);
        CONVST(am0, am1, av0, av1, ae0, ae1, u);
      } else {
        if (i + 1 < UPB) LOADS(am0, am1, av0, av1, ae0, ae1, un);
        CONVST(bm0, bm1, bv0, bv1, be0, be1, u);
      }
    }
#undef GOFS
#undef LOADS
#undef CONVST
  } else if (b < WBLKP + XBLK) {
    // ---- x -> bf16 (6 MB total) ----
    const size_t o = (size_t)(b - WBLKP) * 2048u + 8u * (uint32_t)t;
    f32x4 x0 = *(const f32x4*)(x + o);
    f32x4 x1 = *(const f32x4*)(x + o + 4);
    u32x4 w;
    w[0] = pack2bf(x0[0], x0[1]); w[1] = pack2bf(x0[2], x0[3]);
    w[2] = pack2bf(x1[0], x1[1]); w[3] = pack2bf(x1[2], x1[3]);
    *(u32x4*)(xs + o * 2u) = w;
  } else {
    // ---- bias ----
#pragma unroll
    for (int i = 0; i < 16; ++i) {
      const int j = i * 256 + t;
      bias[j] = fmaf(beps[j], exp2f(blv[j] * HLG), bmu[j]);
    }
  }
}

// ---------------------------------------------------------------------------
// Pass 2: y = xs @ W_bf16^T (+ bias if NSPLIT==1, else fp32 partials).
// (unchanged — validated)
// ---------------------------------------------------------------------------
template<int NSPLIT>
__global__ __launch_bounds__(256, 2)
void vgemm_img(const uint16_t* __restrict__ xs,
               const uint8_t*  __restrict__ wimg,
               const float*    __restrict__ biasp,
               float*          __restrict__ out)
{
  __shared__ __align__(16) uint8_t lds[16384];   // 2 bufs x 2 images x 4 KB

  const int tid = threadIdx.x;
  const int wv  = tid >> 6;
  const int l   = tid & 63;
  const int cg  = blockIdx.x / NSPLIT;
  const int ks  = blockIdx.x % NSPLIT;
  const int nt0 = cg * 2;
  const int KT0 = ks * (32 / NSPLIT);
  const int NIT = 32 / NSPLIT;

  const int br = l & 15;
  const int kb = l >> 4;
  const int arow0 = wv * 64 + br;

  f32x4 acc0[4] = {{0,0,0,0},{0,0,0,0},{0,0,0,0},{0,0,0,0}};
  f32x4 acc1[4] = {{0,0,0,0},{0,0,0,0},{0,0,0,0},{0,0,0,0}};

  auto STAGE = [&](int t, int buf) {
    const int kt = KT0 + t;
#pragma unroll
    for (int j = 0; j < 2; ++j) {
      const int ch = wv * 2 + j;
      const int i  = ch >> 2;
      const int q  = ch & 3;
      const uint8_t* src = wimg + (((size_t)((nt0 + i) * 32 + kt)) << 12)
                                + q * 1024 + l * 16;
      gload_lds16(src, &lds[0] + buf * 8192 + i * 4096 + q * 1024 + l * 16);
    }
  };

  auto COMP = [&](int t, int buf) {
    const uint8_t* B = &lds[0] + buf * 8192;
#pragma unroll
    for (int s = 0; s < 4; ++s) {
      const int swz = br * 256 + ((((s * 4 + kb) ^ br) & 15) << 4);
      bf16x8 b0 = *(const bf16x8*)(B + swz);
      bf16x8 b1 = *(const bf16x8*)(B + 4096 + swz);
      const size_t kk = (size_t)(KT0 + t) * 128 + s * 32 + kb * 8;
#pragma unroll
      for (int j = 0; j < 4; ++j) {
        bf16x8 a = *(const bf16x8*)(xs + (size_t)(arow0 + 16 * j) * IN_F + kk);
        acc0[j] = MFMA(a, b0, acc0[j]);
        acc1[j] = MFMA(a, b1, acc1[j]);
      }
    }
  };

  STAGE(0, 0);
  for (int t = 0; t < NIT; ++t) {
    if (t + 1 < NIT) STAGE(t + 1, (t + 1) & 1);
    __syncthreads();
    COMP(t, t & 1);
    __syncthreads();
  }

#pragma unroll
  for (int img = 0; img < 2; ++img) {
    const f32x4* acc = img ? acc1 : acc0;
    const int col = cg * 32 + img * 16 + br;
    if constexpr (NSPLIT == 1) {
      const float bv = biasp[col];
#pragma unroll
      for (int j = 0; j < 4; ++j) {
        const int rbase = wv * 64 + j * 16 + kb * 4;
#pragma unroll
        for (int i = 0; i < 4; ++i)
          out[(size_t)(rbase + i) * OUT_F + col] = acc[j][i] + bv;
      }
    } else {
      float* po = out + (size_t)ks * BATCH * OUT_F;
#pragma unroll
      for (int j = 0; j < 4; ++j) {
        const int rbase = wv * 64 + j * 16 + kb * 4;
#pragma unroll
        for (int i = 0; i < 4; ++i)
          po[(size_t)(rbase + i) * OUT_F + col] = acc[j][i];
      }
    }
  }
}

// ---------------------------------------------------------------------------
// Fallback prep + fused GEMM (R3 structure) for degraded ws sizes.
// ---------------------------------------------------------------------------
__global__ __launch_bounds__(256) void prep_kernel(
    const float* __restrict__ x,
    const float* __restrict__ bmu,
    const float* __restrict__ blv,
    const float* __restrict__ beps,
    u32x4* __restrict__ xs4,
    float* __restrict__ bias)
{
  const uint32_t b = blockIdx.x;
  if (b < 512u) {
    const uint32_t c = b * 256u + threadIdx.x;
    const float* p = x + (size_t)c * 8u;
    f32x4 v0 = *(const f32x4*)p;
    f32x4 v1 = *(const f32x4*)(p + 4);
    u32x4 o;
    o[0] = pack2bf(v0[0], v0[1]); o[1] = pack2bf(v0[2], v0[3]);
    o[2] = pack2bf(v1[0], v1[1]); o[3] = pack2bf(v1[2], v1[3]);
    xs4[c] = o;
  } else {
    const uint32_t i = (b - 512u) * 256u + threadIdx.x;
    bias[i] = fmaf(beps[i], exp2f(blv[i] * HALF_LOG2E), bmu[i]);
  }
}

#define RAW_BUF   12288
#define RAW_ARR   4096
#define BF_BASE   24576
#define LDS_TOTAL 26624

template<int NSPLIT, bool USE_XS>
__global__ __launch_bounds__(256, 4)
void vgemm3(const uint16_t* __restrict__ xs,
            const float*    __restrict__ xf,
            const float*    __restrict__ wmu,
            const float*    __restrict__ wlv,
            const float*    __restrict__ weps,
            const float*    __restrict__ biasp,
            const float*    __restrict__ bmu,
            const float*    __restrict__ blv,
            const float*    __restrict__ beps,
            float*          __restrict__ out)
{
  __shared__ __align__(16) uint8_t lds[LDS_TOTAL];

  const int tid = threadIdx.x;
  const int wv  = tid >> 6;
  const int l   = tid & 63;
  const int col_tile = blockIdx.x / NSPLIT;
  const int ks       = blockIdx.x % NSPLIT;
  const int n0  = col_tile * 16;
  const int k0  = ks * (IN_F / NSPLIT);
  const int NT  = (IN_F / NSPLIT) / 64;

  const size_t sgoff = (size_t)(n0 + 4 * wv + (l >> 4)) * IN_F + k0 + ((l & 15) << 2);
  const int cr = tid >> 4;
  const int ci = tid & 15;
  const int bfw = cr * 128 + ((((ci >> 1) ^ (cr & 7)) << 4)) + ((ci & 1) << 3);
  const int br = l & 15;
  const int kb = l >> 4;
  const int bfo0 = br * 128 + ((((0 * 4 + kb)) ^ (br & 7)) << 4);
  const int bfo1 = br * 128 + ((((1 * 4 + kb)) ^ (br & 7)) << 4);
  const int arow0 = wv * 64 + br;

  f32x4 acc[4] = {{0,0,0,0},{0,0,0,0},{0,0,0,0},{0,0,0,0}};

  auto STAGE = [&](int t, int buf) {
    const size_t go = sgoff + (size_t)t * 64;
    uint8_t* base = &lds[0] + buf * RAW_BUF + wv * 1024;
    gload_lds16(wmu  + go, base + 0 * RAW_ARR);
    gload_lds16(wlv  + go, base + 1 * RAW_ARR);
    gload_lds16(weps + go, base + 2 * RAW_ARR);
  };
  auto CVT = [&](int buf) {
    const uint8_t* rb = &lds[0] + buf * RAW_BUF;
    f32x4 m = *(const f32x4*)(rb + 0 * RAW_ARR + tid * 16);
    f32x4 v = *(const f32x4*)(rb + 1 * RAW_ARR + tid * 16);
    f32x4 e = *(const f32x4*)(rb + 2 * RAW_ARR + tid * 16);
    u32x2 o;
    o[0] = pack2bf(fmaf(e[0], exp2f(v[0] * HALF_LOG2E), m[0]),
                   fmaf(e[1], exp2f(v[1] * HALF_LOG2E), m[1]));
    o[1] = pack2bf(fmaf(e[2], exp2f(v[2] * HALF_LOG2E), m[2]),
                   fmaf(e[3], exp2f(v[3] * HALF_LOG2E), m[3]));
    *(u32x2*)(&lds[0] + BF_BASE + bfw) = o;
  };
  auto COMP = [&](int t) {
    const uint8_t* bfb = &lds[0] + BF_BASE;
    bf16x8 b0 = *(const bf16x8*)(bfb + bfo0);
    bf16x8 b1 = *(const bf16x8*)(bfb + bfo1);
    const size_t kb0 = (size_t)k0 + t * 64 + kb * 8;
#pragma unroll
    for (int j = 0; j < 4; ++j) {
      bf16x8 a0, a1;
      if constexpr (USE_XS) {
        const uint16_t* xp = xs + (size_t)(arow0 + 16 * j) * IN_F + kb0;
        a0 = *(const bf16x8*)(xp);
        a1 = *(const bf16x8*)(xp + 32);
      } else {
        const float* xp = xf + (size_t)(arow0 + 16 * j) * IN_F + kb0;
        a0 = cvt8(xp);
        a1 = cvt8(xp + 32);
      }
      acc[j] = MFMA(a0, b0, acc[j]);
      acc[j] = MFMA(a1, b1, acc[j]);
    }
  };

  STAGE(0, 0);
  for (int t = 0; t < NT; ++t) {
    if (t + 1 < NT) STAGE(t + 1, (t + 1) & 1);
    __syncthreads();
    CVT(t & 1);
    __syncthreads();
    COMP(t);
  }

  const int col = n0 + br;
  if constexpr (NSPLIT == 1) {
    float bv;
    if constexpr (USE_XS) bv = biasp[col];
    else bv = fmaf(beps[col], exp2f(blv[col] * HALF_LOG2E), bmu[col]);
#pragma unroll
    for (int j = 0; j < 4; ++j) {
      const int rbase = wv * 64 + j * 16 + kb * 4;
#pragma unroll
      for (int i = 0; i < 4; ++i)
        out[(size_t)(rbase + i) * OUT_F + col] = acc[j][i] + bv;
    }
  } else {
    float* po = out + (size_t)ks * BATCH * OUT_F;
#pragma unroll
    for (int j = 0; j < 4; ++j) {
      const int rbase = wv * 64 + j * 16 + kb * 4;
#pragma unroll
      for (int i = 0; i < 4; ++i)
        po[(size_t)(rbase + i) * OUT_F + col] = acc[j][i];
    }
  }
}

// ---------------------------------------------------------------------------
__global__ __launch_bounds__(256) void reduce_kernel(
    const float* __restrict__ parts,
    const float* __restrict__ bias,
    float* __restrict__ y)
{
  const size_t e = ((size_t)blockIdx.x * 256 + threadIdx.x) * 4;
  f32x4 s = *(const f32x4*)(parts + e);
#pragma unroll
  for (int p = 1; p < KSPLIT; ++p)
    s += *(const f32x4*)(parts + (size_t)p * BATCH * OUT_F + e);
  s += *(const f32x4*)(bias + (e & (OUT_F - 1)));
  *(f32x4*)(y + e) = s;
}

// ---------------------------------------------------------------------------
extern "C" void kernel_launch(void* const* d_in, const int* in_sizes, int n_in,
                              void* d_out, int out_size, void* d_ws, size_t ws_size,
                              hipStream_t stream) {
  const float* x    = (const float*)d_in[0];
  const float* wmu  = (const float*)d_in[1];
  const float* wlv  = (const float*)d_in[2];
  const float* bmu  = (const float*)d_in[3];
  const float* blv  = (const float*)d_in[4];
  const float* weps = (const float*)d_in[5];
  const float* beps = (const float*)d_in[6];
  float* y = (float*)d_out;

  const size_t xs_b   = (size_t)BATCH * IN_F * 2;            // 2 MiB
  const size_t bias_b = (size_t)OUT_F * 4;                   // 16 KiB
  const size_t part_b = (size_t)KSPLIT * BATCH * OUT_F * 4;  // 16 MiB
  const size_t img_b  = (size_t)OUT_F * IN_F * 2;            // 32 MiB

  uint16_t* xsp  = (uint16_t*)d_ws;
  float*    bias = (float*)((char*)d_ws + xs_b);

  if (d_ws && ws_size >= xs_b + bias_b + part_b + img_b) {
    float*   parts = (float*)((char*)d_ws + xs_b + bias_b);
    uint8_t* wimg  = (uint8_t*)d_ws + xs_b + bias_b + part_b;
    wcvt_persist<<<WBLKP + XBLK + 1, 256, 0, stream>>>(
        wmu, wlv, weps, x, bmu, blv, beps, wimg, (uint8_t*)xsp, bias);
    vgemm_img<KSPLIT><<<(OUT_F / 32) * KSPLIT, 256, 0, stream>>>(xsp, wimg, bias, parts);
    reduce_kernel<<<(BATCH * OUT_F) / (256 * 4), 256, 0, stream>>>(parts, bias, y);
  } else if (d_ws && ws_size >= xs_b + bias_b + img_b) {
    uint8_t* wimg = (uint8_t*)d_ws + xs_b + bias_b;
    wcvt_persist<<<WBLKP + XBLK + 1, 256, 0, stream>>>(
        wmu, wlv, weps, x, bmu, blv, beps, wimg, (uint8_t*)xsp, bias);
    vgemm_img<1><<<OUT_F / 32, 256, 0, stream>>>(xsp, wimg, bias, y);
  } else if (d_ws && ws_size >= xs_b + bias_b + part_b) {
    float* parts = (float*)((char*)d_ws + xs_b + bias_b);
    prep_kernel<<<528, 256, 0, stream>>>(x, bmu, blv, beps, (u32x4*)d_ws, bias);
    vgemm3<KSPLIT, true><<<(OUT_F / 16) * KSPLIT, 256, 0, stream>>>(
        xsp, nullptr, wmu, wlv, weps, bias, nullptr, nullptr, nullptr, parts);
    reduce_kernel<<<(BATCH * OUT_F) / (256 * 4), 256, 0, stream>>>(parts, bias, y);
  } else if (d_ws && ws_size >= xs_b + bias_b) {
    prep_kernel<<<528, 256, 0, stream>>>(x, bmu, blv, beps, (u32x4*)d_ws, bias);
    vgemm3<1, true><<<OUT_F / 16, 256, 0, stream>>>(
        xsp, nullptr, wmu, wlv, weps, bias, nullptr, nullptr, nullptr, y);
  } else {
    vgemm3<1, false><<<OUT_F / 16, 256, 0, stream>>>(
        nullptr, x, wmu, wlv, weps, nullptr, bmu, blv, beps, y);
  }
}